// Round 4
// baseline (342.321 us; speedup 1.0000x reference)
//
#include <hip/hip_runtime.h>

// LabelizerNet: avg-pool(6,2) -> RGB->HSV -> yellow/blue mask -> per-panel max/min
// Input : states (N, 3, 84, 84) f32   (N = 4096)
// Output: labels (N, 6) f32  [yellow panels 0..2, blue panels 0..2]
//
// Round 4: rolling row-sums. Thread = (image, pair-col, 5-output-row chunk):
// 14 input rows loaded once each (2 float4/row), row-sums reused across the 3
// overlapping 6-row windows. Summation tree bit-identical to round 3.
// 320-thread block = exactly 2 images (160 strips each), no idle lanes.

#define IMG_H 84
#define IMG_W 84
#define CH_ELEMS (IMG_H * IMG_W)   // 7056
#define P_W 40
#define PAIRS_W 20                 // pixel-pair columns
#define OUT_ROWS 5                 // output rows per chunk
#define IN_ROWS 14                 // 2*OUT_ROWS + 4
#define CHUNKS 8                   // 40 / OUT_ROWS
#define ITEMS_PER_IMG 160          // PAIRS_W * CHUNKS
#define THREADS 320                // 2 images per block

__global__ __launch_bounds__(THREADS, 4)
void labelizer_kernel(const float* __restrict__ in, float* __restrict__ out, int N) {
    __shared__ unsigned pb[2];     // panel bits per local image

    const int tid = threadIdx.x;
    if (tid < 2) pb[tid] = 0u;
    __syncthreads();

    const int limg = tid / ITEMS_PER_IMG;          // 0 or 1
    const int item = tid - limg * ITEMS_PER_IMG;   // 0..159
    const int img  = blockIdx.x * 2 + limg;

    unsigned my = 0u;
    int xp = 0;

    if (img < N) {
        const int chunk = item / PAIRS_W;          // 0..7
        xp = item - chunk * PAIRS_W;               // 0..19
        const int R0 = chunk * (2 * OUT_ROWS);     // first input row
        const float* img_ptr = in + (size_t)img * (3 * CH_ELEMS);

        float p0[OUT_ROWS][3], p1[OUT_ROWS][3];
        #pragma unroll
        for (int c = 0; c < 3; ++c) {
            const float* cb = img_ptr + c * CH_ELEMS + R0 * IMG_W + 4 * xp;  // 16B-aligned
            float rs0[IN_ROWS], rs1[IN_ROWS];
            #pragma unroll
            for (int r = 0; r < IN_ROWS; ++r) {
                const float4* rp = (const float4*)(cb + r * IMG_W);
                float4 q0 = rp[0], q1 = rp[1];
                float a01 = q0.x + q0.y;
                float a23 = q0.z + q0.w;
                float a45 = q1.x + q1.y;
                float a67 = q1.z + q1.w;
                rs0[r] = (a01 + a23) + a45;     // window at x = 2*xp
                rs1[r] = (a23 + a45) + a67;     // window at x = 2*xp+1
            }
            #pragma unroll
            for (int o = 0; o < OUT_ROWS; ++o) {
                float t0 = ((rs0[2*o] + rs0[2*o+1]) + (rs0[2*o+2] + rs0[2*o+3]))
                         + (rs0[2*o+4] + rs0[2*o+5]);
                float t1 = ((rs1[2*o] + rs1[2*o+1]) + (rs1[2*o+2] + rs1[2*o+3]))
                         + (rs1[2*o+4] + rs1[2*o+5]);
                p0[o][c] = t0 / 36.0f;
                p1[o][c] = t1 / 36.0f;
            }
        }

        #pragma unroll
        for (int o = 0; o < OUT_ROWS; ++o) {
            #pragma unroll
            for (int e = 0; e < 2; ++e) {
                float r = (e == 0) ? p0[o][0] : p1[o][0];
                float g = (e == 0) ? p0[o][1] : p1[o][1];
                float b = (e == 0) ? p0[o][2] : p1[o][2];

                float maxc = fmaxf(r, fmaxf(g, b));
                float minc = fminf(r, fminf(g, b));
                float delta = maxc - minc;
                float s = (maxc == 0.0f) ? 0.0f : delta / maxc;
                float v = maxc;
                float h = 0.0f;
                if (delta != 0.0f) {
                    float rc = (maxc - r) / delta;
                    float gc = (maxc - g) / delta;
                    float bc = (maxc - b) / delta;
                    float hh = (r == maxc) ? (bc - gc)
                             : ((g == maxc) ? (2.0f + rc - bc)
                                            : (4.0f + gc - rc));
                    h = hh / 6.0f;           // in (-1/6, 5/6); floor-mod 1:
                    if (h < 0.0f) h += 1.0f;
                }
                bool satval = (s > 0.5f) && (v > 0.5f);
                int m = 0;
                if (satval && h >= 0.1f && h <= 0.2f) m = 1;
                else if (satval && h >= 0.55f && h <= 0.7f) m = -1;

                int x = 2 * xp + e;
                if (x < 39) {                 // col 39 excluded (40//3*3 == 39)
                    int pan = x / 13;         // 0..2
                    unsigned bit = (m > 0) ? 1u : (m < 0) ? 2u : 4u;
                    my |= bit << (3 * pan);
                }
            }
        }
    }

    // Butterfly OR within each 32-lane half (image boundary in a wave falls
    // exactly at lane 32: tids 128..159 -> img0, 160..191 -> img1).
    #pragma unroll
    for (int off = 16; off > 0; off >>= 1) my |= __shfl_xor(my, off);
    if ((tid & 31) == 0 && my) atomicOr(&pb[limg], my);
    __syncthreads();

    if (tid < 12) {
        int i = tid / 6;                  // local image
        int j = tid - i * 6;              // output index
        int g = blockIdx.x * 2 + i;
        if (g < N) {
            int pan = (j < 3) ? j : j - 3;
            unsigned w = pb[i] >> (3 * pan);
            bool anyY = w & 1u;
            bool anyB = (w >> 1) & 1u;
            bool anyZ = (w >> 2) & 1u;
            float val;
            if (j < 3) val = anyY ? 1.0f : (anyZ ? 0.0f : -1.0f);   // max(panel)
            else       val = anyB ? 1.0f : (anyZ ? 0.0f : -1.0f);   // -min(panel)
            out[(size_t)g * 6 + j] = val;
        }
    }
}

extern "C" void kernel_launch(void* const* d_in, const int* in_sizes, int n_in,
                              void* d_out, int out_size, void* d_ws, size_t ws_size,
                              hipStream_t stream) {
    const float* states = (const float*)d_in[0];
    float* out = (float*)d_out;
    int N = in_sizes[0] / (3 * CH_ELEMS);   // 4096
    int blocks = (N + 1) / 2;
    labelizer_kernel<<<blocks, THREADS, 0, stream>>>(states, out, N);
}

// Round 5
// 188.053 us; speedup vs baseline: 1.8203x; 1.8203x over previous
//
#include <hip/hip_runtime.h>

// LabelizerNet: avg-pool(6,2) -> RGB->HSV -> yellow/blue mask -> per-panel max/min
// Input : states (N, 3, 84, 84) f32   (N = 4096)
// Output: labels (N, 6) f32  [yellow panels 0..2, blue panels 0..2]
//
// Round 5: round-4 rolling row-sums, but WITHOUT the VGPR clamp.
// Round 4's __launch_bounds__(320,4) forced VGPR=64 -> ~1 GB scratch spill
// traffic (WRITE_SIZE 479 MB). (320,2) gives the ~100-VGPR live set room.

#define IMG_H 84
#define IMG_W 84
#define CH_ELEMS (IMG_H * IMG_W)   // 7056
#define P_W 40
#define PAIRS_W 20                 // pixel-pair columns
#define OUT_ROWS 5                 // output rows per chunk
#define IN_ROWS 14                 // 2*OUT_ROWS + 4
#define CHUNKS 8                   // 40 / OUT_ROWS
#define ITEMS_PER_IMG 160          // PAIRS_W * CHUNKS
#define THREADS 320                // 2 images per block

__global__ __launch_bounds__(THREADS, 2)
void labelizer_kernel(const float* __restrict__ in, float* __restrict__ out, int N) {
    __shared__ unsigned pb[2];     // panel bits per local image

    const int tid = threadIdx.x;
    if (tid < 2) pb[tid] = 0u;
    __syncthreads();

    const int limg = tid / ITEMS_PER_IMG;          // 0 or 1
    const int item = tid - limg * ITEMS_PER_IMG;   // 0..159
    const int img  = blockIdx.x * 2 + limg;

    unsigned my = 0u;
    int xp = 0;

    if (img < N) {
        const int chunk = item / PAIRS_W;          // 0..7
        xp = item - chunk * PAIRS_W;               // 0..19
        const int R0 = chunk * (2 * OUT_ROWS);     // first input row
        const float* img_ptr = in + (size_t)img * (3 * CH_ELEMS);

        float p0[OUT_ROWS][3], p1[OUT_ROWS][3];
        #pragma unroll
        for (int c = 0; c < 3; ++c) {
            const float* cb = img_ptr + c * CH_ELEMS + R0 * IMG_W + 4 * xp;  // 16B-aligned
            float rs0[IN_ROWS], rs1[IN_ROWS];
            #pragma unroll
            for (int r = 0; r < IN_ROWS; ++r) {
                const float4* rp = (const float4*)(cb + r * IMG_W);
                float4 q0 = rp[0], q1 = rp[1];
                float a01 = q0.x + q0.y;
                float a23 = q0.z + q0.w;
                float a45 = q1.x + q1.y;
                float a67 = q1.z + q1.w;
                rs0[r] = (a01 + a23) + a45;     // window at x = 2*xp
                rs1[r] = (a23 + a45) + a67;     // window at x = 2*xp+1
            }
            #pragma unroll
            for (int o = 0; o < OUT_ROWS; ++o) {
                float t0 = ((rs0[2*o] + rs0[2*o+1]) + (rs0[2*o+2] + rs0[2*o+3]))
                         + (rs0[2*o+4] + rs0[2*o+5]);
                float t1 = ((rs1[2*o] + rs1[2*o+1]) + (rs1[2*o+2] + rs1[2*o+3]))
                         + (rs1[2*o+4] + rs1[2*o+5]);
                p0[o][c] = t0 / 36.0f;
                p1[o][c] = t1 / 36.0f;
            }
        }

        #pragma unroll
        for (int o = 0; o < OUT_ROWS; ++o) {
            #pragma unroll
            for (int e = 0; e < 2; ++e) {
                float r = (e == 0) ? p0[o][0] : p1[o][0];
                float g = (e == 0) ? p0[o][1] : p1[o][1];
                float b = (e == 0) ? p0[o][2] : p1[o][2];

                float maxc = fmaxf(r, fmaxf(g, b));
                float minc = fminf(r, fminf(g, b));
                float delta = maxc - minc;
                float s = (maxc == 0.0f) ? 0.0f : delta / maxc;
                float v = maxc;
                float h = 0.0f;
                if (delta != 0.0f) {
                    float rc = (maxc - r) / delta;
                    float gc = (maxc - g) / delta;
                    float bc = (maxc - b) / delta;
                    float hh = (r == maxc) ? (bc - gc)
                             : ((g == maxc) ? (2.0f + rc - bc)
                                            : (4.0f + gc - rc));
                    h = hh / 6.0f;           // in (-1/6, 5/6); floor-mod 1:
                    if (h < 0.0f) h += 1.0f;
                }
                bool satval = (s > 0.5f) && (v > 0.5f);
                int m = 0;
                if (satval && h >= 0.1f && h <= 0.2f) m = 1;
                else if (satval && h >= 0.55f && h <= 0.7f) m = -1;

                int x = 2 * xp + e;
                if (x < 39) {                 // col 39 excluded (40//3*3 == 39)
                    int pan = x / 13;         // 0..2
                    unsigned bit = (m > 0) ? 1u : (m < 0) ? 2u : 4u;
                    my |= bit << (3 * pan);
                }
            }
        }
    }

    // Butterfly OR within each 32-lane half (image boundary in a wave falls
    // exactly at lane 32: tids 128..159 -> img0, 160..191 -> img1).
    #pragma unroll
    for (int off = 16; off > 0; off >>= 1) my |= __shfl_xor(my, off);
    if ((tid & 31) == 0 && my) atomicOr(&pb[limg], my);
    __syncthreads();

    if (tid < 12) {
        int i = tid / 6;                  // local image
        int j = tid - i * 6;              // output index
        int g = blockIdx.x * 2 + i;
        if (g < N) {
            int pan = (j < 3) ? j : j - 3;
            unsigned w = pb[i] >> (3 * pan);
            bool anyY = w & 1u;
            bool anyB = (w >> 1) & 1u;
            bool anyZ = (w >> 2) & 1u;
            float val;
            if (j < 3) val = anyY ? 1.0f : (anyZ ? 0.0f : -1.0f);   // max(panel)
            else       val = anyB ? 1.0f : (anyZ ? 0.0f : -1.0f);   // -min(panel)
            out[(size_t)g * 6 + j] = val;
        }
    }
}

extern "C" void kernel_launch(void* const* d_in, const int* in_sizes, int n_in,
                              void* d_out, int out_size, void* d_ws, size_t ws_size,
                              hipStream_t stream) {
    const float* states = (const float*)d_in[0];
    float* out = (float*)d_out;
    int N = in_sizes[0] / (3 * CH_ELEMS);   // 4096
    int blocks = (N + 1) / 2;
    labelizer_kernel<<<blocks, THREADS, 0, stream>>>(states, out, N);
}

// Round 6
// 114.194 us; speedup vs baseline: 2.9977x; 1.6468x over previous
//
#include <hip/hip_runtime.h>

// LabelizerNet: avg-pool(6,2) -> RGB->HSV -> yellow/blue mask -> per-panel max/min
// Input : states (N, 3, 84, 84) f32   (N = 4096)
// Output: labels (N, 6) f32  [yellow panels 0..2, blue panels 0..2]
//
// Round 6: streaming row-pair pipeline. Window sum (P_o + P_{o+1}) + P_{o+2}
// over row-pair sums P_j = rs[2j] + rs[2j+1] -- bit-identical grouping to the
// reference tree -- with only {prevP, prevS} x {3ch} x {2 windows} = 12 floats
// of rolling state. No per-thread arrays survive -> no scratch spill (round 5's
// 153 MB WRITE_SIZE was spill at the 128-VGPR cap).

#define IMG_H 84
#define IMG_W 84
#define CH_ELEMS (IMG_H * IMG_W)   // 7056
#define PAIRS_W 20                 // pixel-pair columns
#define OUT_ROWS 5                 // output rows per chunk
#define ROW_PAIRS 7                // input row-pairs per chunk (rows 0..13)
#define CHUNKS 8                   // 40 / OUT_ROWS
#define ITEMS_PER_IMG 160          // PAIRS_W * CHUNKS
#define THREADS 320                // 2 images per block

__global__ __launch_bounds__(THREADS, 2)
void labelizer_kernel(const float* __restrict__ in, float* __restrict__ out, int N) {
    __shared__ unsigned pb[2];     // panel bits per local image

    const int tid = threadIdx.x;
    if (tid < 2) pb[tid] = 0u;
    __syncthreads();

    const int limg = tid / ITEMS_PER_IMG;          // 0 or 1
    const int item = tid - limg * ITEMS_PER_IMG;   // 0..159
    const int img  = blockIdx.x * 2 + limg;

    unsigned my = 0u;

    if (img < N) {
        const int chunk = item / PAIRS_W;          // 0..7
        const int xp = item - chunk * PAIRS_W;     // 0..19
        const int x0 = 2 * xp, x1 = 2 * xp + 1;
        const int R0 = chunk * (2 * OUT_ROWS);     // first input row
        const float* cb0 = in + (size_t)img * (3 * CH_ELEMS) + R0 * IMG_W + 4 * xp;

        float prevP0[3], prevS0[3], prevP1[3], prevS1[3];

        #pragma unroll
        for (int j = 0; j < ROW_PAIRS; ++j) {
            float t0[3], t1[3];
            #pragma unroll
            for (int c = 0; c < 3; ++c) {
                const float* rbase = cb0 + c * CH_ELEMS + (2 * j) * IMG_W;
                const float4* ra = (const float4*)rbase;            // row 2j
                const float4* rb = (const float4*)(rbase + IMG_W);  // row 2j+1
                float4 qa0 = ra[0], qa1 = ra[1];
                float4 qb0 = rb[0], qb1 = rb[1];
                float a01 = qa0.x + qa0.y, a23 = qa0.z + qa0.w;
                float a45 = qa1.x + qa1.y, a67 = qa1.z + qa1.w;
                float rsa0 = (a01 + a23) + a45;      // rs[2j],  window x0
                float rsa1 = (a23 + a45) + a67;      // rs[2j],  window x1
                float b01 = qb0.x + qb0.y, b23 = qb0.z + qb0.w;
                float b45 = qb1.x + qb1.y, b67 = qb1.z + qb1.w;
                float rsb0 = (b01 + b23) + b45;      // rs[2j+1], window x0
                float rsb1 = (b23 + b45) + b67;      // rs[2j+1], window x1
                float P0 = rsa0 + rsb0;              // pair sum == rs[2j]+rs[2j+1]
                float P1 = rsa1 + rsb1;
                if (j >= 2) {                        // finalize output row o=j-2
                    t0[c] = prevS0[c] + P0;          // (P_o+P_{o+1}) + P_{o+2}
                    t1[c] = prevS1[c] + P1;
                }
                if (j >= 1) {
                    prevS0[c] = prevP0[c] + P0;      // P_{j-1} + P_j
                    prevS1[c] = prevP1[c] + P1;
                }
                prevP0[c] = P0;
                prevP1[c] = P1;
            }
            if (j >= 2) {
                #pragma unroll
                for (int e = 0; e < 2; ++e) {
                    float r = ((e == 0) ? t0[0] : t1[0]) / 36.0f;
                    float g = ((e == 0) ? t0[1] : t1[1]) / 36.0f;
                    float b = ((e == 0) ? t0[2] : t1[2]) / 36.0f;

                    float maxc = fmaxf(r, fmaxf(g, b));
                    float minc = fminf(r, fminf(g, b));
                    float delta = maxc - minc;
                    float s = (maxc == 0.0f) ? 0.0f : delta / maxc;
                    float v = maxc;
                    float h = 0.0f;
                    if (delta != 0.0f) {
                        float rc = (maxc - r) / delta;
                        float gc = (maxc - g) / delta;
                        float bc = (maxc - b) / delta;
                        float hh = (r == maxc) ? (bc - gc)
                                 : ((g == maxc) ? (2.0f + rc - bc)
                                                : (4.0f + gc - rc));
                        h = hh / 6.0f;           // in (-1/6, 5/6); floor-mod 1:
                        if (h < 0.0f) h += 1.0f;
                    }
                    bool satval = (s > 0.5f) && (v > 0.5f);
                    int m = 0;
                    if (satval && h >= 0.1f && h <= 0.2f) m = 1;
                    else if (satval && h >= 0.55f && h <= 0.7f) m = -1;

                    int x = (e == 0) ? x0 : x1;
                    if (x < 39) {                 // col 39 excluded (40//3*3 == 39)
                        int pan = x / 13;         // 0..2
                        unsigned bit = (m > 0) ? 1u : (m < 0) ? 2u : 4u;
                        my |= bit << (3 * pan);
                    }
                }
            }
        }
    }

    // Butterfly OR within each 32-lane half (image boundary in a wave falls
    // exactly at lane 32: tids 128..159 -> img0, 160..191 -> img1).
    #pragma unroll
    for (int off = 16; off > 0; off >>= 1) my |= __shfl_xor(my, off);
    if ((tid & 31) == 0 && my) atomicOr(&pb[limg], my);
    __syncthreads();

    if (tid < 12) {
        int i = tid / 6;                  // local image
        int j = tid - i * 6;              // output index
        int g = blockIdx.x * 2 + i;
        if (g < N) {
            int pan = (j < 3) ? j : j - 3;
            unsigned w = pb[i] >> (3 * pan);
            bool anyY = w & 1u;
            bool anyB = (w >> 1) & 1u;
            bool anyZ = (w >> 2) & 1u;
            float val;
            if (j < 3) val = anyY ? 1.0f : (anyZ ? 0.0f : -1.0f);   // max(panel)
            else       val = anyB ? 1.0f : (anyZ ? 0.0f : -1.0f);   // -min(panel)
            out[(size_t)g * 6 + j] = val;
        }
    }
}

extern "C" void kernel_launch(void* const* d_in, const int* in_sizes, int n_in,
                              void* d_out, int out_size, void* d_ws, size_t ws_size,
                              hipStream_t stream) {
    const float* states = (const float*)d_in[0];
    float* out = (float*)d_out;
    int N = in_sizes[0] / (3 * CH_ELEMS);   // 4096
    int blocks = (N + 1) / 2;
    labelizer_kernel<<<blocks, THREADS, 0, stream>>>(states, out, N);
}

// Round 7
// 112.605 us; speedup vs baseline: 3.0400x; 1.0141x over previous
//
#include <hip/hip_runtime.h>

// LabelizerNet: avg-pool(6,2) -> RGB->HSV -> yellow/blue mask -> per-panel max/min
// Input : states (N, 3, 84, 84) f32   (N = 4096)
// Output: labels (N, 6) f32  [yellow panels 0..2, blue panels 0..2]
//
// Round 7: occupancy attack. Single-wave (64-thread) blocks, no LDS, no
// barriers; per-image 9-bit mask accumulated in d_ws via device-scope
// atomicOr; tiny finalize kernel writes the 6 floats. Streaming row-pair
// math body is verbatim round 6 (bit-identical results).

#define IMG_H 84
#define IMG_W 84
#define CH_ELEMS (IMG_H * IMG_W)   // 7056
#define PAIRS_W 20                 // pixel-pair columns
#define ROW_PAIRS 7                // input row-pairs per chunk (rows 0..13)
#define ITEMS_PER_IMG 160          // PAIRS_W * 8 chunks

__global__ __launch_bounds__(64, 4)
void pool_mask_kernel(const float* __restrict__ in, unsigned* __restrict__ ws,
                      int total_items) {
    const int lane = threadIdx.x;
    const int gi = blockIdx.x * 64 + lane;

    const int img  = gi / ITEMS_PER_IMG;
    const int item = gi - img * ITEMS_PER_IMG;

    unsigned my = 0u;

    if (gi < total_items) {
        const int chunk = item / PAIRS_W;          // 0..7
        const int xp = item - chunk * PAIRS_W;     // 0..19
        const int x0 = 2 * xp, x1 = 2 * xp + 1;
        const int R0 = chunk * 10;                 // first input row
        const float* cb0 = in + (size_t)img * (3 * CH_ELEMS) + R0 * IMG_W + 4 * xp;

        float prevP0[3], prevS0[3], prevP1[3], prevS1[3];

        #pragma unroll
        for (int j = 0; j < ROW_PAIRS; ++j) {
            float t0[3], t1[3];
            #pragma unroll
            for (int c = 0; c < 3; ++c) {
                const float* rbase = cb0 + c * CH_ELEMS + (2 * j) * IMG_W;
                const float4* ra = (const float4*)rbase;            // row 2j
                const float4* rb = (const float4*)(rbase + IMG_W);  // row 2j+1
                float4 qa0 = ra[0], qa1 = ra[1];
                float4 qb0 = rb[0], qb1 = rb[1];
                float a01 = qa0.x + qa0.y, a23 = qa0.z + qa0.w;
                float a45 = qa1.x + qa1.y, a67 = qa1.z + qa1.w;
                float rsa0 = (a01 + a23) + a45;      // rs[2j],  window x0
                float rsa1 = (a23 + a45) + a67;      // rs[2j],  window x1
                float b01 = qb0.x + qb0.y, b23 = qb0.z + qb0.w;
                float b45 = qb1.x + qb1.y, b67 = qb1.z + qb1.w;
                float rsb0 = (b01 + b23) + b45;      // rs[2j+1], window x0
                float rsb1 = (b23 + b45) + b67;      // rs[2j+1], window x1
                float P0 = rsa0 + rsb0;              // pair sum == rs[2j]+rs[2j+1]
                float P1 = rsa1 + rsb1;
                if (j >= 2) {                        // finalize output row o=j-2
                    t0[c] = prevS0[c] + P0;          // (P_o+P_{o+1}) + P_{o+2}
                    t1[c] = prevS1[c] + P1;
                }
                if (j >= 1) {
                    prevS0[c] = prevP0[c] + P0;      // P_{j-1} + P_j
                    prevS1[c] = prevP1[c] + P1;
                }
                prevP0[c] = P0;
                prevP1[c] = P1;
            }
            if (j >= 2) {
                #pragma unroll
                for (int e = 0; e < 2; ++e) {
                    float r = ((e == 0) ? t0[0] : t1[0]) / 36.0f;
                    float g = ((e == 0) ? t0[1] : t1[1]) / 36.0f;
                    float b = ((e == 0) ? t0[2] : t1[2]) / 36.0f;

                    float maxc = fmaxf(r, fmaxf(g, b));
                    float minc = fminf(r, fminf(g, b));
                    float delta = maxc - minc;
                    float s = (maxc == 0.0f) ? 0.0f : delta / maxc;
                    float v = maxc;
                    float h = 0.0f;
                    if (delta != 0.0f) {
                        float rc = (maxc - r) / delta;
                        float gc = (maxc - g) / delta;
                        float bc = (maxc - b) / delta;
                        float hh = (r == maxc) ? (bc - gc)
                                 : ((g == maxc) ? (2.0f + rc - bc)
                                                : (4.0f + gc - rc));
                        h = hh / 6.0f;           // in (-1/6, 5/6); floor-mod 1:
                        if (h < 0.0f) h += 1.0f;
                    }
                    bool satval = (s > 0.5f) && (v > 0.5f);
                    int m = 0;
                    if (satval && h >= 0.1f && h <= 0.2f) m = 1;
                    else if (satval && h >= 0.55f && h <= 0.7f) m = -1;

                    int x = (e == 0) ? x0 : x1;
                    if (x < 39) {                 // col 39 excluded (40//3*3 == 39)
                        int pan = x / 13;         // 0..2
                        unsigned bit = (m > 0) ? 1u : (m < 0) ? 2u : 4u;
                        my |= bit << (3 * pan);
                    }
                }
            }
        }
    }

    // A wave spans at most 2 images (64 < 160). Reduce each separately.
    const int imgA = __shfl(img, 0);
    const int imgB = __shfl(img, 63);
    unsigned vA = (img == imgA) ? my : 0u;
    #pragma unroll
    for (int off = 32; off > 0; off >>= 1) vA |= __shfl_xor(vA, off);
    if (lane == 0 && vA) atomicOr(&ws[imgA], vA);
    if (imgB != imgA) {
        unsigned vB = (img == imgB) ? my : 0u;
        #pragma unroll
        for (int off = 32; off > 0; off >>= 1) vB |= __shfl_xor(vB, off);
        if (lane == 0 && vB) atomicOr(&ws[imgB], vB);
    }
}

__global__ __launch_bounds__(256)
void finalize_kernel(const unsigned* __restrict__ ws, float* __restrict__ out, int N) {
    int i = blockIdx.x * 256 + threadIdx.x;
    if (i < N * 6) {
        int img = i / 6;
        int j = i - img * 6;
        int pan = (j < 3) ? j : j - 3;
        unsigned w = ws[img] >> (3 * pan);
        bool anyY = w & 1u;
        bool anyB = (w >> 1) & 1u;
        bool anyZ = (w >> 2) & 1u;
        float val;
        if (j < 3) val = anyY ? 1.0f : (anyZ ? 0.0f : -1.0f);   // max(panel)
        else       val = anyB ? 1.0f : (anyZ ? 0.0f : -1.0f);   // -min(panel)
        out[i] = val;
    }
}

extern "C" void kernel_launch(void* const* d_in, const int* in_sizes, int n_in,
                              void* d_out, int out_size, void* d_ws, size_t ws_size,
                              hipStream_t stream) {
    const float* states = (const float*)d_in[0];
    float* out = (float*)d_out;
    unsigned* ws = (unsigned*)d_ws;
    int N = in_sizes[0] / (3 * CH_ELEMS);   // 4096
    int total_items = N * ITEMS_PER_IMG;    // 655360

    hipMemsetAsync(ws, 0, (size_t)N * sizeof(unsigned), stream);
    int blocks1 = (total_items + 63) / 64;  // 10240
    pool_mask_kernel<<<blocks1, 64, 0, stream>>>(states, ws, total_items);
    int blocks2 = (N * 6 + 255) / 256;
    finalize_kernel<<<blocks2, 256, 0, stream>>>(ws, out, N);
}